// Round 11
// baseline (91.670 us; speedup 1.0000x reference)
//
#include <hip/hip_runtime.h>
#include <hip/hip_bf16.h>
#include <hip/hip_fp16.h>

#define BDIM    128   // batch size, fixed by problem
#define NGROUPS 2     // batch groups (64 batches each), one per XCD quad
#define GCOLS   64    // batch columns per group
#define ROWB    (GCOLS * 2)            // bytes per xTh row = 128 (one L2 line)
#define EBLK    2048  // edge-kernel blocks (divisible by 8)
#define RANKS   (EBLK / NGROUPS)       // blocks per group = 1024
#define CHUNK   512   // edges staged in LDS per block iteration (2 sub-chunks)
#define S1BLK   (NGROUPS * 8)          // stage-1 edge-reduce blocks = 16
#define HBLK2   8     // stage-1 h-reduce blocks
#define RPS     (RANKS / 8)            // ranks per stage-1 block = 128

// ---------------------------------------------------------------------------
// Kernel 1: transpose+convert x (B=128,N) f32 -> xTh[g][N][64] fp16 slices,
// FUSED with h-term partials. Read phase is float4 (1KB per wave-instruction);
// LDS write banks (4c+m+b)%32 spread 2-way (free). Tail block zero-fills.
// ---------------------------------------------------------------------------
__global__ __launch_bounds__(256) void transpose_h_kernel(
    const float* __restrict__ x, const float* __restrict__ h,
    __half* __restrict__ xTh, float* __restrict__ hp, int N) {
  __shared__ float tile[64][BDIM + 1];
  __shared__ float sh[64];
  __shared__ float red2[2][BDIM];
  const int tid = threadIdx.x;
  const int n0  = blockIdx.x * 64;

  // read: thread (c = n-quad 0..15, b0 = 0..15); 8 passes over b
  const int c     = tid & 15;
  const int b0    = tid >> 4;
  const int nbase = n0 + 4 * c;
#pragma unroll
  for (int p = 0; p < 8; ++p) {
    const int b = b0 + 16 * p;
    float4 v;
    if (nbase + 3 < N) {
      v = *(const float4*)&x[(size_t)b * N + nbase];
    } else {
      v.x = (nbase + 0 < N) ? x[(size_t)b * N + nbase + 0] : 0.f;
      v.y = (nbase + 1 < N) ? x[(size_t)b * N + nbase + 1] : 0.f;
      v.z = (nbase + 2 < N) ? x[(size_t)b * N + nbase + 2] : 0.f;
      v.w = (nbase + 3 < N) ? x[(size_t)b * N + nbase + 3] : 0.f;
    }
    tile[4 * c + 0][b] = v.x;
    tile[4 * c + 1][b] = v.y;
    tile[4 * c + 2][b] = v.z;
    tile[4 * c + 3][b] = v.w;
  }
  if (tid < 64) sh[tid] = (n0 + tid < N) ? h[n0 + tid] : 0.f;
  __syncthreads();

  // h-term partial: thread (half, b) sums 32 n's
  const int hb   = tid & 127;
  const int half = tid >> 7;
  float hacc = 0.f;
#pragma unroll
  for (int m = 0; m < 32; ++m) {
    const int nl = half * 32 + m;
    hacc += tile[nl][hb] * sh[nl];
  }
  red2[half][hb] = hacc;

  // transpose store: thread = (k, g2, c2); 32 lanes write 128B contiguous
  const int c2 = tid & 31;
  const int g2 = (tid >> 5) & 1;
  const int k  = tid >> 6;
  for (int it = 0; it < 16; ++it) {
    const int nl = it * 4 + k;
    if (n0 + nl < N) {
      const float a = tile[nl][g2 * GCOLS + 2 * c2];
      const float b = tile[nl][g2 * GCOLS + 2 * c2 + 1];
      __half2* dst = (__half2*)(xTh + ((size_t)g2 * N + (n0 + nl)) * GCOLS + 2 * c2);
      *dst = __floats2half2_rn(a, b);
    }
  }
  __syncthreads();
  if (tid < BDIM) hp[(size_t)blockIdx.x * BDIM + tid] = red2[0][tid] + red2[1][tid];
}

// ---------------------------------------------------------------------------
// 8-column fp16 product with v_fma_mix_f32 accumulate.
// ---------------------------------------------------------------------------
__device__ __forceinline__ void fma8mix(float* acc, int4 vi, int4 vj, float Jv) {
  const int wi[4] = {vi.x, vi.y, vi.z, vi.w};
  const int wj[4] = {vj.x, vj.y, vj.z, vj.w};
#pragma unroll
  for (int w = 0; w < 4; ++w) {
    const __half2 hi = __builtin_bit_cast(__half2, wi[w]);
    const __half2 hj = __builtin_bit_cast(__half2, wj[w]);
    const int p = __builtin_bit_cast(int, __hmul2(hi, hj));
    asm("v_fma_mix_f32 %0, %1, %2, %0 op_sel_hi:[1,0,0]"
        : "+v"(acc[2 * w]) : "v"(p), "v"(Jv));
    asm("v_fma_mix_f32 %0, %1, %2, %0 op_sel:[1,0,0] op_sel_hi:[1,0,0]"
        : "+v"(acc[2 * w + 1]) : "v"(p), "v"(Jv));
  }
}

// ---------------------------------------------------------------------------
// Kernel 2: edge interactions. 8 lanes per edge, 16B/lane of a 128B row ->
// one aligned L2 line per row access. CHUNK=512 staged in LDS per iteration;
// per sub-chunk all 16 row gathers are issued as one cluster pinned by
// sched_barrier(0) before the consume cluster (16 lines in flight/wave).
// Two sub-chunks per barrier pair -> half the sync overhead of CHUNK=256.
// Block -> (group, rank): g=(blockIdx&7)>>2 -> XCD quad; slice 6.4MB.
// ---------------------------------------------------------------------------
__global__ __launch_bounds__(256, 4) void edge_kernel(
    const __half* __restrict__ xTh, const float* __restrict__ J,
    const int* __restrict__ ei, const int* __restrict__ ej,
    float* __restrict__ P, int E, int N) {
  const int tid  = threadIdx.x;
  const int g    = (blockIdx.x & 7) >> 2;
  const int rank = (blockIdx.x >> 3) * 4 + (blockIdx.x & 3);
  const int wave = tid >> 6;
  const int lane = tid & 63;
  const int k    = lane >> 3;          // edge sub-index 0..7
  const char* xgl = (const char*)xTh + (size_t)g * N * ROWB + (lane & 7) * 16;

  const int TC    = (E + CHUNK - 1) / CHUNK;  // total chunks
  const int start = (int)(((long)rank * TC / RANKS)) * CHUNK;
  const int end   = min((int)(((long)(rank + 1) * TC / RANKS)) * CHUNK, E);

  __shared__ int4 se[CHUNK];

  // register prefetch of first chunk (issue early, write late)
  int ri0 = 0, rj0 = 0, ri1 = 0, rj1 = 0;
  float rJ0 = 0.f, rJ1 = 0.f;
  {
    const int e0 = start + tid;
    const int e1 = start + 256 + tid;
    if (e0 < end) { ri0 = ei[e0]; rj0 = ej[e0]; rJ0 = J[e0]; }
    if (e1 < end) { ri1 = ei[e1]; rj1 = ej[e1]; rJ1 = J[e1]; }
  }

  float acc[8] = {0.f, 0.f, 0.f, 0.f, 0.f, 0.f, 0.f, 0.f};

  for (int base = start; base < end; base += CHUNK) {
    se[tid]       = make_int4(ri0, rj0, __float_as_int(rJ0), 0);
    se[tid + 256] = make_int4(ri1, rj1, __float_as_int(rJ1), 0);
    __syncthreads();

    // issue next chunk's index loads; latency hides under this whole chunk
    {
      const int e0 = base + CHUNK + tid;
      const int e1 = base + CHUNK + 256 + tid;
      ri0 = 0; rj0 = 0; rJ0 = 0.f;
      ri1 = 0; rj1 = 0; rJ1 = 0.f;
      if (e0 < end) { ri0 = ei[e0]; rj0 = ej[e0]; rJ0 = J[e0]; }
      if (e1 < end) { ri1 = ei[e1]; rj1 = ej[e1]; rJ1 = J[e1]; }
    }

    const int lbase = wave * 64 + k;
#pragma unroll
    for (int half = 0; half < 2; ++half) {
      const int hb = half * 256 + lbase;
      // ---- issue cluster: 8 LDS descriptor reads + 16 row gathers ----
      const int4 eA0 = se[hb + 0 * 8];
      const int4 eA1 = se[hb + 1 * 8];
      const int4 eA2 = se[hb + 2 * 8];
      const int4 eA3 = se[hb + 3 * 8];
      const int4 viA0 = *(const int4*)(xgl + (unsigned)eA0.x * ROWB);
      const int4 vjA0 = *(const int4*)(xgl + (unsigned)eA0.y * ROWB);
      const int4 viA1 = *(const int4*)(xgl + (unsigned)eA1.x * ROWB);
      const int4 vjA1 = *(const int4*)(xgl + (unsigned)eA1.y * ROWB);
      const int4 viA2 = *(const int4*)(xgl + (unsigned)eA2.x * ROWB);
      const int4 vjA2 = *(const int4*)(xgl + (unsigned)eA2.y * ROWB);
      const int4 viA3 = *(const int4*)(xgl + (unsigned)eA3.x * ROWB);
      const int4 vjA3 = *(const int4*)(xgl + (unsigned)eA3.y * ROWB);
      const int4 eB0 = se[hb + 4 * 8];
      const int4 eB1 = se[hb + 5 * 8];
      const int4 eB2 = se[hb + 6 * 8];
      const int4 eB3 = se[hb + 7 * 8];
      const int4 viB0 = *(const int4*)(xgl + (unsigned)eB0.x * ROWB);
      const int4 vjB0 = *(const int4*)(xgl + (unsigned)eB0.y * ROWB);
      const int4 viB1 = *(const int4*)(xgl + (unsigned)eB1.x * ROWB);
      const int4 vjB1 = *(const int4*)(xgl + (unsigned)eB1.y * ROWB);
      const int4 viB2 = *(const int4*)(xgl + (unsigned)eB2.x * ROWB);
      const int4 vjB2 = *(const int4*)(xgl + (unsigned)eB2.y * ROWB);
      const int4 viB3 = *(const int4*)(xgl + (unsigned)eB3.x * ROWB);
      const int4 vjB3 = *(const int4*)(xgl + (unsigned)eB3.y * ROWB);
      __builtin_amdgcn_sched_barrier(0);
      // ---- consume cluster ----
      fma8mix(acc, viA0, vjA0, __int_as_float(eA0.z));
      fma8mix(acc, viA1, vjA1, __int_as_float(eA1.z));
      fma8mix(acc, viA2, vjA2, __int_as_float(eA2.z));
      fma8mix(acc, viA3, vjA3, __int_as_float(eA3.z));
      fma8mix(acc, viB0, vjB0, __int_as_float(eB0.z));
      fma8mix(acc, viB1, vjB1, __int_as_float(eB1.z));
      fma8mix(acc, viB2, vjB2, __int_as_float(eB2.z));
      fma8mix(acc, viB3, vjB3, __int_as_float(eB3.z));
    }
    __syncthreads();
  }

  // combine the 8 k-lanes sharing each column eighth (xor 8,16,32)
#pragma unroll
  for (int off = 8; off < 64; off <<= 1)
#pragma unroll
    for (int w = 0; w < 8; ++w) acc[w] += __shfl_xor(acc[w], off);

  __shared__ float red[4][GCOLS];
  if (lane < 8)
#pragma unroll
    for (int w = 0; w < 8; ++w) red[wave][lane * 8 + w] = acc[w];
  __syncthreads();
  if (tid < GCOLS) {
    const float s = red[0][tid] + red[1][tid] + red[2][tid] + red[3][tid];
    P[((size_t)g * RANKS + rank) * GCOLS + tid] = s;
  }
}

// ---------------------------------------------------------------------------
// Kernel 3: stage-1 reduce. Blocks [0,16): edge partials (g,s) sum 128 rank
// rows -> P2. Blocks [16,24): h partials, block s sums rows r%8==s -> hp2.
// ---------------------------------------------------------------------------
__global__ __launch_bounds__(256) void reduce1_kernel(
    const float* __restrict__ P, const float* __restrict__ hp,
    float* __restrict__ P2, float* __restrict__ hp2, int hrows) {
  __shared__ float red[4][GCOLS];
  __shared__ float redh[2][BDIM];
  if (blockIdx.x < S1BLK) {
    const int g  = blockIdx.x >> 3;
    const int s  = blockIdx.x & 7;
    const int rl = threadIdx.x >> 6;  // 0..3
    const int c  = threadIdx.x & 63;
    float acc = 0.f;
    for (int rr = rl; rr < RPS; rr += 4)
      acc += P[((size_t)g * RANKS + s * RPS + rr) * GCOLS + c];
    red[rl][c] = acc;
    __syncthreads();
    if (threadIdx.x < GCOLS) {
      float sum = 0.f;
      for (int r = 0; r < 4; ++r) sum += red[r][threadIdx.x];
      P2[(size_t)blockIdx.x * GCOLS + threadIdx.x] = sum;
    }
  } else {
    const int s  = blockIdx.x - S1BLK;   // 0..7
    const int b  = threadIdx.x & 127;
    const int rg = threadIdx.x >> 7;
    float acc = 0.f;
    for (int r = s + 8 * rg; r < hrows; r += 16)
      acc += hp[(size_t)r * BDIM + b];
    redh[rg][b] = acc;
    __syncthreads();
    if (threadIdx.x < BDIM)
      hp2[(size_t)s * BDIM + threadIdx.x] = redh[0][threadIdx.x] + redh[1][threadIdx.x];
  }
}

// ---------------------------------------------------------------------------
// Kernel 4: final: out[b] = sum_s hp2[s][b] + sum_s P2[(g*8+s)][c].
// ---------------------------------------------------------------------------
__global__ __launch_bounds__(128) void reduce2_kernel(
    const float* __restrict__ P2, const float* __restrict__ hp2,
    float* __restrict__ out) {
  const int b = threadIdx.x;
  const int g = b >> 6;
  const int c = b & 63;
  float acc = 0.f;
  for (int s = 0; s < 8; ++s) acc += hp2[(size_t)s * BDIM + b];
  for (int s = 0; s < 8; ++s) acc += P2[(size_t)(g * 8 + s) * GCOLS + c];
  out[b] = acc;
}

extern "C" void kernel_launch(void* const* d_in, const int* in_sizes, int n_in,
                              void* d_out, int out_size, void* d_ws, size_t ws_size,
                              hipStream_t stream) {
  const float* x  = (const float*)d_in[0];
  const float* h  = (const float*)d_in[1];
  const float* J  = (const float*)d_in[2];
  const int*   ei = (const int*)d_in[3];
  const int*   ej = (const int*)d_in[4];
  float* out = (float*)d_out;

  const int N = in_sizes[1];   // 50000
  const int E = in_sizes[2];   // 1600000

  const int tblocks = (N + 63) / 64;

  // ws layout: xTh (2*N*64 halves) | P (2048*64) | P2 (16*64) | hp (tblocks*128) | hp2 (8*128)
  __half* xTh = (__half*)d_ws;
  float* P   = (float*)(xTh + (size_t)NGROUPS * N * GCOLS);
  float* P2  = P   + (size_t)NGROUPS * RANKS * GCOLS;
  float* hp  = P2  + (size_t)S1BLK * GCOLS;
  float* hp2 = hp  + (size_t)tblocks * BDIM;

  // 1) transpose + fp16 convert + h-term partials (float4 read phase)
  transpose_h_kernel<<<tblocks, 256, 0, stream>>>(x, h, xTh, hp, N);

  // 2) edge interactions (2 groups, XCD-quad affine, 128B lines, pinned MLP,
  //    CHUNK=512 -> half the barrier overhead)
  edge_kernel<<<EBLK, 256, 0, stream>>>(xTh, J, ei, ej, P, E, N);

  // 3) stage-1 reduce (edge partials + h partials)
  reduce1_kernel<<<S1BLK + HBLK2, 256, 0, stream>>>(P, hp, P2, hp2, tblocks);

  // 4) final deterministic reduce (overwrites d_out)
  reduce2_kernel<<<1, BDIM, 0, stream>>>(P2, hp2, out);
}

// Round 12
// 80.812 us; speedup vs baseline: 1.1344x; 1.1344x over previous
//
#include <hip/hip_runtime.h>
#include <hip/hip_bf16.h>
#include <hip/hip_fp16.h>

#define BDIM    128   // batch size, fixed by problem
#define NGROUPS 2     // batch groups (64 batches each), one per XCD quad
#define GCOLS   64    // batch columns per group
#define ROWB    (GCOLS * 2)            // bytes per xTh row = 128 (one L2 line)
#define EBLK    2048  // edge-kernel blocks (divisible by 8)
#define RANKS   (EBLK / NGROUPS)       // blocks per group = 1024
#define CHUNK   256   // edges staged in LDS per block iteration
#define S1BLK   (NGROUPS * 8)          // stage-1 edge-reduce blocks = 16
#define HBLK2   8     // stage-1 h-reduce blocks
#define RPS     (RANKS / 8)            // ranks per stage-1 block = 128
#define TPAD    132   // tile row stride (floats): 16B-aligned, banks <=4-way

// ---------------------------------------------------------------------------
// Kernel 1: transpose+convert x (B=128,N) f32 -> xTh[g][N][64] fp16 slices,
// FUSED with h-term partials. Read phase: float4 (1KB/wave-inst). Store
// phase: 2x ds_read_b128 + pack + one 16B coalesced store per item, 4 passes.
// ---------------------------------------------------------------------------
__global__ __launch_bounds__(256) void transpose_h_kernel(
    const float* __restrict__ x, const float* __restrict__ h,
    __half* __restrict__ xTh, float* __restrict__ hp, int N) {
  __shared__ float tile[64 * TPAD];
  __shared__ float sh[64];
  __shared__ float red2[2][BDIM];
  const int tid = threadIdx.x;
  const int n0  = blockIdx.x * 64;

  // read: thread (c = n-quad 0..15, b0 = 0..15); 8 passes over b
  const int c     = tid & 15;
  const int b0    = tid >> 4;
  const int nbase = n0 + 4 * c;
#pragma unroll
  for (int p = 0; p < 8; ++p) {
    const int b = b0 + 16 * p;
    float4 v;
    if (nbase + 3 < N) {
      v = *(const float4*)&x[(size_t)b * N + nbase];
    } else {
      v.x = (nbase + 0 < N) ? x[(size_t)b * N + nbase + 0] : 0.f;
      v.y = (nbase + 1 < N) ? x[(size_t)b * N + nbase + 1] : 0.f;
      v.z = (nbase + 2 < N) ? x[(size_t)b * N + nbase + 2] : 0.f;
      v.w = (nbase + 3 < N) ? x[(size_t)b * N + nbase + 3] : 0.f;
    }
    tile[(4 * c + 0) * TPAD + b] = v.x;
    tile[(4 * c + 1) * TPAD + b] = v.y;
    tile[(4 * c + 2) * TPAD + b] = v.z;
    tile[(4 * c + 3) * TPAD + b] = v.w;
  }
  if (tid < 64) sh[tid] = (n0 + tid < N) ? h[n0 + tid] : 0.f;
  __syncthreads();

  // h-term partial: thread (half, b) sums 32 n's (stride-1 LDS reads)
  const int hb   = tid & 127;
  const int half = tid >> 7;
  float hacc = 0.f;
#pragma unroll
  for (int m = 0; m < 32; ++m) {
    const int nl = half * 32 + m;
    hacc += tile[nl * TPAD + hb] * sh[nl];
  }
  red2[half][hb] = hacc;

  // store: thread = (oct 0..7, g2 0..1, r0 0..15); 4 passes over rows.
  // 2x ds_read_b128 -> 4x cvt_pk -> one 16B global store (8 lanes = 128B row)
  const int oct = tid & 7;
  const int g2  = (tid >> 3) & 1;
  const int r0  = tid >> 4;
#pragma unroll
  for (int p = 0; p < 4; ++p) {
    const int nl = r0 + 16 * p;
    const int n  = n0 + nl;
    if (n < N) {
      const float* src = &tile[nl * TPAD + g2 * GCOLS + oct * 8];
      const float4 lo = *(const float4*)(src);
      const float4 hi = *(const float4*)(src + 4);
      int4 outv;
      outv.x = __builtin_bit_cast(int, __floats2half2_rn(lo.x, lo.y));
      outv.y = __builtin_bit_cast(int, __floats2half2_rn(lo.z, lo.w));
      outv.z = __builtin_bit_cast(int, __floats2half2_rn(hi.x, hi.y));
      outv.w = __builtin_bit_cast(int, __floats2half2_rn(hi.z, hi.w));
      *(int4*)(xTh + ((size_t)g2 * N + n) * GCOLS + oct * 8) = outv;
    }
  }
  __syncthreads();
  if (tid < BDIM) hp[(size_t)blockIdx.x * BDIM + tid] = red2[0][tid] + red2[1][tid];
}

// ---------------------------------------------------------------------------
// 8-column fp16 product with v_fma_mix_f32 accumulate.
// ---------------------------------------------------------------------------
__device__ __forceinline__ void fma8mix(float* acc, int4 vi, int4 vj, float Jv) {
  const int wi[4] = {vi.x, vi.y, vi.z, vi.w};
  const int wj[4] = {vj.x, vj.y, vj.z, vj.w};
#pragma unroll
  for (int w = 0; w < 4; ++w) {
    const __half2 hi = __builtin_bit_cast(__half2, wi[w]);
    const __half2 hj = __builtin_bit_cast(__half2, wj[w]);
    const int p = __builtin_bit_cast(int, __hmul2(hi, hj));
    asm("v_fma_mix_f32 %0, %1, %2, %0 op_sel_hi:[1,0,0]"
        : "+v"(acc[2 * w]) : "v"(p), "v"(Jv));
    asm("v_fma_mix_f32 %0, %1, %2, %0 op_sel:[1,0,0] op_sel_hi:[1,0,0]"
        : "+v"(acc[2 * w + 1]) : "v"(p), "v"(Jv));
  }
}

// ---------------------------------------------------------------------------
// Kernel 2: edge interactions — exact R10 configuration (proven 54.4us).
// 8 lanes per edge, 16B/lane of a 128B row -> one aligned L2 line per row
// access. Per chunk-step ALL 16 row gathers issued as one cluster pinned by
// sched_barrier(0) before the consume cluster. CHUNK=256 (VGPR sweet spot;
// CHUNK=512 spilled, R11). Block -> (group, rank): g=(blockIdx&7)>>2 ->
// XCD quad; 6.4MB slice quad-L2-resident.
// ---------------------------------------------------------------------------
__global__ __launch_bounds__(256, 4) void edge_kernel(
    const __half* __restrict__ xTh, const float* __restrict__ J,
    const int* __restrict__ ei, const int* __restrict__ ej,
    float* __restrict__ P, int E, int N) {
  const int tid  = threadIdx.x;
  const int g    = (blockIdx.x & 7) >> 2;
  const int rank = (blockIdx.x >> 3) * 4 + (blockIdx.x & 3);
  const int wave = tid >> 6;
  const int lane = tid & 63;
  const int k    = lane >> 3;          // edge sub-index 0..7
  const char* xgl = (const char*)xTh + (size_t)g * N * ROWB + (lane & 7) * 16;

  const int TC    = (E + CHUNK - 1) / CHUNK;  // total chunks
  const int start = (int)(((long)rank * TC / RANKS)) * CHUNK;
  const int end   = min((int)(((long)(rank + 1) * TC / RANKS)) * CHUNK, E);

  __shared__ int4 se[CHUNK];

  // register prefetch of first chunk (issue early, write late)
  int ri = 0, rj = 0;
  float rJ = 0.f;
  {
    const int e = start + tid;
    if (e < end) { ri = ei[e]; rj = ej[e]; rJ = J[e]; }
  }

  float acc[8] = {0.f, 0.f, 0.f, 0.f, 0.f, 0.f, 0.f, 0.f};

  for (int base = start; base < end; base += CHUNK) {
    se[tid] = make_int4(ri, rj, __float_as_int(rJ), 0);
    __syncthreads();

    // issue next chunk's index loads; latency hides under this whole chunk
    {
      const int e = base + CHUNK + tid;
      ri = 0; rj = 0; rJ = 0.f;
      if (e < end) { ri = ei[e]; rj = ej[e]; rJ = J[e]; }
    }

    const int lbase = wave * 64 + k;
    // ---- issue cluster: 8 LDS descriptor reads + 16 row gathers ----
    const int4 eA0 = se[lbase + 0 * 8];
    const int4 eA1 = se[lbase + 1 * 8];
    const int4 eA2 = se[lbase + 2 * 8];
    const int4 eA3 = se[lbase + 3 * 8];
    const int4 viA0 = *(const int4*)(xgl + (unsigned)eA0.x * ROWB);
    const int4 vjA0 = *(const int4*)(xgl + (unsigned)eA0.y * ROWB);
    const int4 viA1 = *(const int4*)(xgl + (unsigned)eA1.x * ROWB);
    const int4 vjA1 = *(const int4*)(xgl + (unsigned)eA1.y * ROWB);
    const int4 viA2 = *(const int4*)(xgl + (unsigned)eA2.x * ROWB);
    const int4 vjA2 = *(const int4*)(xgl + (unsigned)eA2.y * ROWB);
    const int4 viA3 = *(const int4*)(xgl + (unsigned)eA3.x * ROWB);
    const int4 vjA3 = *(const int4*)(xgl + (unsigned)eA3.y * ROWB);
    const int4 eB0 = se[lbase + 4 * 8];
    const int4 eB1 = se[lbase + 5 * 8];
    const int4 eB2 = se[lbase + 6 * 8];
    const int4 eB3 = se[lbase + 7 * 8];
    const int4 viB0 = *(const int4*)(xgl + (unsigned)eB0.x * ROWB);
    const int4 vjB0 = *(const int4*)(xgl + (unsigned)eB0.y * ROWB);
    const int4 viB1 = *(const int4*)(xgl + (unsigned)eB1.x * ROWB);
    const int4 vjB1 = *(const int4*)(xgl + (unsigned)eB1.y * ROWB);
    const int4 viB2 = *(const int4*)(xgl + (unsigned)eB2.x * ROWB);
    const int4 vjB2 = *(const int4*)(xgl + (unsigned)eB2.y * ROWB);
    const int4 viB3 = *(const int4*)(xgl + (unsigned)eB3.x * ROWB);
    const int4 vjB3 = *(const int4*)(xgl + (unsigned)eB3.y * ROWB);
    __builtin_amdgcn_sched_barrier(0);
    // ---- consume cluster ----
    fma8mix(acc, viA0, vjA0, __int_as_float(eA0.z));
    fma8mix(acc, viA1, vjA1, __int_as_float(eA1.z));
    fma8mix(acc, viA2, vjA2, __int_as_float(eA2.z));
    fma8mix(acc, viA3, vjA3, __int_as_float(eA3.z));
    fma8mix(acc, viB0, vjB0, __int_as_float(eB0.z));
    fma8mix(acc, viB1, vjB1, __int_as_float(eB1.z));
    fma8mix(acc, viB2, vjB2, __int_as_float(eB2.z));
    fma8mix(acc, viB3, vjB3, __int_as_float(eB3.z));
    __syncthreads();
  }

  // combine the 8 k-lanes sharing each column eighth (xor 8,16,32)
#pragma unroll
  for (int off = 8; off < 64; off <<= 1)
#pragma unroll
    for (int w = 0; w < 8; ++w) acc[w] += __shfl_xor(acc[w], off);

  __shared__ float red[4][GCOLS];
  if (lane < 8)
#pragma unroll
    for (int w = 0; w < 8; ++w) red[wave][lane * 8 + w] = acc[w];
  __syncthreads();
  if (tid < GCOLS) {
    const float s = red[0][tid] + red[1][tid] + red[2][tid] + red[3][tid];
    P[((size_t)g * RANKS + rank) * GCOLS + tid] = s;
  }
}

// ---------------------------------------------------------------------------
// Kernel 3: stage-1 reduce. Blocks [0,16): edge partials (g,s) sum 128 rank
// rows -> P2. Blocks [16,24): h partials, block s sums rows r%8==s -> hp2.
// ---------------------------------------------------------------------------
__global__ __launch_bounds__(256) void reduce1_kernel(
    const float* __restrict__ P, const float* __restrict__ hp,
    float* __restrict__ P2, float* __restrict__ hp2, int hrows) {
  __shared__ float red[4][GCOLS];
  __shared__ float redh[2][BDIM];
  if (blockIdx.x < S1BLK) {
    const int g  = blockIdx.x >> 3;
    const int s  = blockIdx.x & 7;
    const int rl = threadIdx.x >> 6;  // 0..3
    const int c  = threadIdx.x & 63;
    float acc = 0.f;
    for (int rr = rl; rr < RPS; rr += 4)
      acc += P[((size_t)g * RANKS + s * RPS + rr) * GCOLS + c];
    red[rl][c] = acc;
    __syncthreads();
    if (threadIdx.x < GCOLS) {
      float sum = 0.f;
      for (int r = 0; r < 4; ++r) sum += red[r][threadIdx.x];
      P2[(size_t)blockIdx.x * GCOLS + threadIdx.x] = sum;
    }
  } else {
    const int s  = blockIdx.x - S1BLK;   // 0..7
    const int b  = threadIdx.x & 127;
    const int rg = threadIdx.x >> 7;
    float acc = 0.f;
    for (int r = s + 8 * rg; r < hrows; r += 16)
      acc += hp[(size_t)r * BDIM + b];
    redh[rg][b] = acc;
    __syncthreads();
    if (threadIdx.x < BDIM)
      hp2[(size_t)s * BDIM + threadIdx.x] = redh[0][threadIdx.x] + redh[1][threadIdx.x];
  }
}

// ---------------------------------------------------------------------------
// Kernel 4: final: out[b] = sum_s hp2[s][b] + sum_s P2[(g*8+s)][c].
// ---------------------------------------------------------------------------
__global__ __launch_bounds__(128) void reduce2_kernel(
    const float* __restrict__ P2, const float* __restrict__ hp2,
    float* __restrict__ out) {
  const int b = threadIdx.x;
  const int g = b >> 6;
  const int c = b & 63;
  float acc = 0.f;
  for (int s = 0; s < 8; ++s) acc += hp2[(size_t)s * BDIM + b];
  for (int s = 0; s < 8; ++s) acc += P2[(size_t)(g * 8 + s) * GCOLS + c];
  out[b] = acc;
}

extern "C" void kernel_launch(void* const* d_in, const int* in_sizes, int n_in,
                              void* d_out, int out_size, void* d_ws, size_t ws_size,
                              hipStream_t stream) {
  const float* x  = (const float*)d_in[0];
  const float* h  = (const float*)d_in[1];
  const float* J  = (const float*)d_in[2];
  const int*   ei = (const int*)d_in[3];
  const int*   ej = (const int*)d_in[4];
  float* out = (float*)d_out;

  const int N = in_sizes[1];   // 50000
  const int E = in_sizes[2];   // 1600000

  const int tblocks = (N + 63) / 64;

  // ws layout: xTh (2*N*64 halves) | P (2048*64) | P2 (16*64) | hp (tblocks*128) | hp2 (8*128)
  __half* xTh = (__half*)d_ws;
  float* P   = (float*)(xTh + (size_t)NGROUPS * N * GCOLS);
  float* P2  = P   + (size_t)NGROUPS * RANKS * GCOLS;
  float* hp  = P2  + (size_t)S1BLK * GCOLS;
  float* hp2 = hp  + (size_t)tblocks * BDIM;

  // 1) transpose + fp16 convert + h-term partials (wide read AND write)
  transpose_h_kernel<<<tblocks, 256, 0, stream>>>(x, h, xTh, hp, N);

  // 2) edge interactions (exact R10 config: CHUNK=256, pinned 16-gather cluster)
  edge_kernel<<<EBLK, 256, 0, stream>>>(xTh, J, ei, ej, P, E, N);

  // 3) stage-1 reduce (edge partials + h partials)
  reduce1_kernel<<<S1BLK + HBLK2, 256, 0, stream>>>(P, hp, P2, hp2, tblocks);

  // 4) final deterministic reduce (overwrites d_out)
  reduce2_kernel<<<1, BDIM, 0, stream>>>(P2, hp2, out);
}

// Round 13
// 79.529 us; speedup vs baseline: 1.1527x; 1.0161x over previous
//
#include <hip/hip_runtime.h>
#include <hip/hip_bf16.h>
#include <hip/hip_fp16.h>

#define BDIM    128   // batch size, fixed by problem
#define NGROUPS 2     // batch groups (64 batches each), one per XCD quad
#define GCOLS   64    // batch columns per group
#define ROWB    (GCOLS * 2)            // bytes per xTh row = 128 (one L2 line)
#define EBLK    2048  // edge-kernel blocks (divisible by 8)
#define RANKS   (EBLK / NGROUPS)       // blocks per group = 1024
#define WPG     (RANKS * 4)            // waves per group = 4096
#define S1BLK   (NGROUPS * 8)          // stage-1 edge-reduce blocks = 16
#define HBLK2   8     // stage-1 h-reduce blocks
#define RPS     (RANKS / 8)            // ranks per stage-1 block = 128
#define TPAD    132   // tile row stride (floats): 16B-aligned, banks <=4-way

// ---------------------------------------------------------------------------
// Kernel 1: transpose+convert x (B=128,N) f32 -> xTh[g][N][64] fp16 slices,
// FUSED with h-term partials. Read: float4. Store: 2x ds_read_b128 + pack +
// one 16B coalesced store, 4 passes. (unchanged from R12)
// ---------------------------------------------------------------------------
__global__ __launch_bounds__(256) void transpose_h_kernel(
    const float* __restrict__ x, const float* __restrict__ h,
    __half* __restrict__ xTh, float* __restrict__ hp, int N) {
  __shared__ float tile[64 * TPAD];
  __shared__ float sh[64];
  __shared__ float red2[2][BDIM];
  const int tid = threadIdx.x;
  const int n0  = blockIdx.x * 64;

  const int c     = tid & 15;
  const int b0    = tid >> 4;
  const int nbase = n0 + 4 * c;
#pragma unroll
  for (int p = 0; p < 8; ++p) {
    const int b = b0 + 16 * p;
    float4 v;
    if (nbase + 3 < N) {
      v = *(const float4*)&x[(size_t)b * N + nbase];
    } else {
      v.x = (nbase + 0 < N) ? x[(size_t)b * N + nbase + 0] : 0.f;
      v.y = (nbase + 1 < N) ? x[(size_t)b * N + nbase + 1] : 0.f;
      v.z = (nbase + 2 < N) ? x[(size_t)b * N + nbase + 2] : 0.f;
      v.w = (nbase + 3 < N) ? x[(size_t)b * N + nbase + 3] : 0.f;
    }
    tile[(4 * c + 0) * TPAD + b] = v.x;
    tile[(4 * c + 1) * TPAD + b] = v.y;
    tile[(4 * c + 2) * TPAD + b] = v.z;
    tile[(4 * c + 3) * TPAD + b] = v.w;
  }
  if (tid < 64) sh[tid] = (n0 + tid < N) ? h[n0 + tid] : 0.f;
  __syncthreads();

  const int hb   = tid & 127;
  const int half = tid >> 7;
  float hacc = 0.f;
#pragma unroll
  for (int m = 0; m < 32; ++m) {
    const int nl = half * 32 + m;
    hacc += tile[nl * TPAD + hb] * sh[nl];
  }
  red2[half][hb] = hacc;

  const int oct = tid & 7;
  const int g2  = (tid >> 3) & 1;
  const int r0  = tid >> 4;
#pragma unroll
  for (int p = 0; p < 4; ++p) {
    const int nl = r0 + 16 * p;
    const int n  = n0 + nl;
    if (n < N) {
      const float* src = &tile[nl * TPAD + g2 * GCOLS + oct * 8];
      const float4 lo = *(const float4*)(src);
      const float4 hi = *(const float4*)(src + 4);
      int4 outv;
      outv.x = __builtin_bit_cast(int, __floats2half2_rn(lo.x, lo.y));
      outv.y = __builtin_bit_cast(int, __floats2half2_rn(lo.z, lo.w));
      outv.z = __builtin_bit_cast(int, __floats2half2_rn(hi.x, hi.y));
      outv.w = __builtin_bit_cast(int, __floats2half2_rn(hi.z, hi.w));
      *(int4*)(xTh + ((size_t)g2 * N + n) * GCOLS + oct * 8) = outv;
    }
  }
  __syncthreads();
  if (tid < BDIM) hp[(size_t)blockIdx.x * BDIM + tid] = red2[0][tid] + red2[1][tid];
}

// ---------------------------------------------------------------------------
// 8-column fp16 product with v_fma_mix_f32 accumulate.
// ---------------------------------------------------------------------------
__device__ __forceinline__ void fma8mix(float* acc, int4 vi, int4 vj, float Jv) {
  const int wi[4] = {vi.x, vi.y, vi.z, vi.w};
  const int wj[4] = {vj.x, vj.y, vj.z, vj.w};
#pragma unroll
  for (int w = 0; w < 4; ++w) {
    const __half2 hi = __builtin_bit_cast(__half2, wi[w]);
    const __half2 hj = __builtin_bit_cast(__half2, wj[w]);
    const int p = __builtin_bit_cast(int, __hmul2(hi, hj));
    asm("v_fma_mix_f32 %0, %1, %2, %0 op_sel_hi:[1,0,0]"
        : "+v"(acc[2 * w]) : "v"(p), "v"(Jv));
    asm("v_fma_mix_f32 %0, %1, %2, %0 op_sel:[1,0,0] op_sel_hi:[1,0,0]"
        : "+v"(acc[2 * w + 1]) : "v"(p), "v"(Jv));
  }
}

// ---------------------------------------------------------------------------
// Kernel 2: edge interactions — barrier-free + shuffle-distributed + pinned
// gather cluster. Each wave owns a contiguous 64-edge-aligned range; per
// 64-edge iteration: each lane loads its own (i,j,J) (coalesced), 24 __shfl
// broadcast the 8-lane-group triples (no LDS, no barriers), then 16 row
// gathers issued as one cluster pinned by sched_barrier(0), then 8 fma8mix.
// Next iteration's index loads are double-buffered in registers. Only the
// globally-last chunk masks with J=0. Block->(group,rank) as before:
// g=(blockIdx&7)>>2 -> XCD quad; 6.4MB fp16 slice quad-L2-resident.
// ---------------------------------------------------------------------------
__global__ __launch_bounds__(256, 4) void edge_kernel(
    const __half* __restrict__ xTh, const float* __restrict__ J,
    const int* __restrict__ ei, const int* __restrict__ ej,
    float* __restrict__ P, int E, int N) {
  const int tid  = threadIdx.x;
  const int g    = (blockIdx.x & 7) >> 2;
  const int rank = (blockIdx.x >> 3) * 4 + (blockIdx.x & 3);
  const int wave = tid >> 6;
  const int lane = tid & 63;
  const int k    = lane >> 3;          // edge sub-index 0..7
  const char* xgl = (const char*)xTh + (size_t)g * N * ROWB + (lane & 7) * 16;

  const int  wi   = rank * 4 + wave;          // wave id within group [0, WPG)
  const long TC   = (E + 63) >> 6;            // total 64-edge chunks
  int base = (int)((long)wi * TC / WPG) * 64;
  const int bend = (int)((long)(wi + 1) * TC / WPG) * 64;  // may exceed E at global end

  float acc[8] = {0.f, 0.f, 0.f, 0.f, 0.f, 0.f, 0.f, 0.f};

  // prefetch iteration 0's indices
  int ri = 0, rj = 0;
  float rJ = 0.f;
  if (base < bend) {
    const int e  = base + lane;
    const int ec = min(e, E - 1);
    ri = ei[ec]; rj = ej[ec]; rJ = (e < E) ? J[ec] : 0.f;
  }

  for (; base < bend; base += 64) {
    const int ci = ri, cj = rj;
    const float cJ = rJ;
    // double-buffer: issue next iteration's index loads now
    {
      const int nb = base + 64;
      if (nb < bend) {
        const int e  = nb + lane;
        const int ec = min(e, E - 1);
        ri = ei[ec]; rj = ej[ec]; rJ = (e < E) ? J[ec] : 0.f;
      }
    }

    // shuffle-distribute the 8 sub-steps' (i,j,J) (srcLane = u*8 + k)
    const int   i0 = __shfl(ci, 0 * 8 + k), j0 = __shfl(cj, 0 * 8 + k);
    const int   i1 = __shfl(ci, 1 * 8 + k), j1 = __shfl(cj, 1 * 8 + k);
    const int   i2 = __shfl(ci, 2 * 8 + k), j2 = __shfl(cj, 2 * 8 + k);
    const int   i3 = __shfl(ci, 3 * 8 + k), j3 = __shfl(cj, 3 * 8 + k);
    const int   i4 = __shfl(ci, 4 * 8 + k), j4 = __shfl(cj, 4 * 8 + k);
    const int   i5 = __shfl(ci, 5 * 8 + k), j5 = __shfl(cj, 5 * 8 + k);
    const int   i6 = __shfl(ci, 6 * 8 + k), j6 = __shfl(cj, 6 * 8 + k);
    const int   i7 = __shfl(ci, 7 * 8 + k), j7 = __shfl(cj, 7 * 8 + k);
    const float J0 = __shfl(cJ, 0 * 8 + k), J1 = __shfl(cJ, 1 * 8 + k);
    const float J2 = __shfl(cJ, 2 * 8 + k), J3 = __shfl(cJ, 3 * 8 + k);
    const float J4 = __shfl(cJ, 4 * 8 + k), J5 = __shfl(cJ, 5 * 8 + k);
    const float J6 = __shfl(cJ, 6 * 8 + k), J7 = __shfl(cJ, 7 * 8 + k);

    // ---- issue cluster: 16 row gathers ----
    const int4 vi0 = *(const int4*)(xgl + (unsigned)i0 * ROWB);
    const int4 vj0 = *(const int4*)(xgl + (unsigned)j0 * ROWB);
    const int4 vi1 = *(const int4*)(xgl + (unsigned)i1 * ROWB);
    const int4 vj1 = *(const int4*)(xgl + (unsigned)j1 * ROWB);
    const int4 vi2 = *(const int4*)(xgl + (unsigned)i2 * ROWB);
    const int4 vj2 = *(const int4*)(xgl + (unsigned)j2 * ROWB);
    const int4 vi3 = *(const int4*)(xgl + (unsigned)i3 * ROWB);
    const int4 vj3 = *(const int4*)(xgl + (unsigned)j3 * ROWB);
    const int4 vi4 = *(const int4*)(xgl + (unsigned)i4 * ROWB);
    const int4 vj4 = *(const int4*)(xgl + (unsigned)j4 * ROWB);
    const int4 vi5 = *(const int4*)(xgl + (unsigned)i5 * ROWB);
    const int4 vj5 = *(const int4*)(xgl + (unsigned)j5 * ROWB);
    const int4 vi6 = *(const int4*)(xgl + (unsigned)i6 * ROWB);
    const int4 vj6 = *(const int4*)(xgl + (unsigned)j6 * ROWB);
    const int4 vi7 = *(const int4*)(xgl + (unsigned)i7 * ROWB);
    const int4 vj7 = *(const int4*)(xgl + (unsigned)j7 * ROWB);
    __builtin_amdgcn_sched_barrier(0);
    // ---- consume cluster ----
    fma8mix(acc, vi0, vj0, J0);
    fma8mix(acc, vi1, vj1, J1);
    fma8mix(acc, vi2, vj2, J2);
    fma8mix(acc, vi3, vj3, J3);
    fma8mix(acc, vi4, vj4, J4);
    fma8mix(acc, vi5, vj5, J5);
    fma8mix(acc, vi6, vj6, J6);
    fma8mix(acc, vi7, vj7, J7);
  }

  // combine the 8 k-lanes sharing each column eighth (xor 8,16,32)
#pragma unroll
  for (int off = 8; off < 64; off <<= 1)
#pragma unroll
    for (int w = 0; w < 8; ++w) acc[w] += __shfl_xor(acc[w], off);

  __shared__ float red[4][GCOLS];
  if (lane < 8)
#pragma unroll
    for (int w = 0; w < 8; ++w) red[wave][lane * 8 + w] = acc[w];
  __syncthreads();
  if (tid < GCOLS) {
    const float s = red[0][tid] + red[1][tid] + red[2][tid] + red[3][tid];
    P[((size_t)g * RANKS + rank) * GCOLS + tid] = s;
  }
}

// ---------------------------------------------------------------------------
// Kernel 3: stage-1 reduce. Blocks [0,16): edge partials (g,s) sum 128 rank
// rows -> P2. Blocks [16,24): h partials, block s sums rows r%8==s -> hp2.
// ---------------------------------------------------------------------------
__global__ __launch_bounds__(256) void reduce1_kernel(
    const float* __restrict__ P, const float* __restrict__ hp,
    float* __restrict__ P2, float* __restrict__ hp2, int hrows) {
  __shared__ float red[4][GCOLS];
  __shared__ float redh[2][BDIM];
  if (blockIdx.x < S1BLK) {
    const int g  = blockIdx.x >> 3;
    const int s  = blockIdx.x & 7;
    const int rl = threadIdx.x >> 6;  // 0..3
    const int c  = threadIdx.x & 63;
    float acc = 0.f;
    for (int rr = rl; rr < RPS; rr += 4)
      acc += P[((size_t)g * RANKS + s * RPS + rr) * GCOLS + c];
    red[rl][c] = acc;
    __syncthreads();
    if (threadIdx.x < GCOLS) {
      float sum = 0.f;
      for (int r = 0; r < 4; ++r) sum += red[r][threadIdx.x];
      P2[(size_t)blockIdx.x * GCOLS + threadIdx.x] = sum;
    }
  } else {
    const int s  = blockIdx.x - S1BLK;   // 0..7
    const int b  = threadIdx.x & 127;
    const int rg = threadIdx.x >> 7;
    float acc = 0.f;
    for (int r = s + 8 * rg; r < hrows; r += 16)
      acc += hp[(size_t)r * BDIM + b];
    redh[rg][b] = acc;
    __syncthreads();
    if (threadIdx.x < BDIM)
      hp2[(size_t)s * BDIM + threadIdx.x] = redh[0][threadIdx.x] + redh[1][threadIdx.x];
  }
}

// ---------------------------------------------------------------------------
// Kernel 4: final: out[b] = sum_s hp2[s][b] + sum_s P2[(g*8+s)][c].
// ---------------------------------------------------------------------------
__global__ __launch_bounds__(128) void reduce2_kernel(
    const float* __restrict__ P2, const float* __restrict__ hp2,
    float* __restrict__ out) {
  const int b = threadIdx.x;
  const int g = b >> 6;
  const int c = b & 63;
  float acc = 0.f;
  for (int s = 0; s < 8; ++s) acc += hp2[(size_t)s * BDIM + b];
  for (int s = 0; s < 8; ++s) acc += P2[(size_t)(g * 8 + s) * GCOLS + c];
  out[b] = acc;
}

extern "C" void kernel_launch(void* const* d_in, const int* in_sizes, int n_in,
                              void* d_out, int out_size, void* d_ws, size_t ws_size,
                              hipStream_t stream) {
  const float* x  = (const float*)d_in[0];
  const float* h  = (const float*)d_in[1];
  const float* J  = (const float*)d_in[2];
  const int*   ei = (const int*)d_in[3];
  const int*   ej = (const int*)d_in[4];
  float* out = (float*)d_out;

  const int N = in_sizes[1];   // 50000
  const int E = in_sizes[2];   // 1600000

  const int tblocks = (N + 63) / 64;

  // ws layout: xTh (2*N*64 halves) | P (2048*64) | P2 (16*64) | hp (tblocks*128) | hp2 (8*128)
  __half* xTh = (__half*)d_ws;
  float* P   = (float*)(xTh + (size_t)NGROUPS * N * GCOLS);
  float* P2  = P   + (size_t)NGROUPS * RANKS * GCOLS;
  float* hp  = P2  + (size_t)S1BLK * GCOLS;
  float* hp2 = hp  + (size_t)tblocks * BDIM;

  // 1) transpose + fp16 convert + h-term partials
  transpose_h_kernel<<<tblocks, 256, 0, stream>>>(x, h, xTh, hp, N);

  // 2) edge interactions (barrier-free, shuffle-distributed, pinned gathers)
  edge_kernel<<<EBLK, 256, 0, stream>>>(xTh, J, ei, ej, P, E, N);

  // 3) stage-1 reduce (edge partials + h partials)
  reduce1_kernel<<<S1BLK + HBLK2, 256, 0, stream>>>(P, hp, P2, hp2, tblocks);

  // 4) final deterministic reduce (overwrites d_out)
  reduce2_kernel<<<1, BDIM, 0, stream>>>(P2, hp2, out);
}